// Round 5
// baseline (79.413 us; speedup 1.0000x reference)
//
#include <hip/hip_runtime.h>
#include <hip/hip_bf16.h>

#define NN 8192
#define D_IN 128
#define D_OUT 64
#define GAT_ALPHA 0.2f
#define LOG2E 1.4426950408889634f

typedef __attribute__((ext_vector_type(4))) float f32x4;
typedef __attribute__((ext_vector_type(8))) short short8;

static __device__ __forceinline__ unsigned short f32_bf16(float f) {
    unsigned u = __builtin_bit_cast(unsigned, f);
    u += 0x7fffu + ((u >> 16) & 1u);   // round-to-nearest-even
    return (unsigned short)(u >> 16);
}

// ---- Kernel 1 (fused): blocks 0..2047 compress adj -> bitmask (streaming);
//      blocks 2048..2559 do prep (wh = h@w, projections, K-blocked bf16 whB) ----
__global__ __launch_bounds__(256) void gat_pre(
    const int* __restrict__ adj, unsigned char* __restrict__ bm,
    const float* __restrict__ h, const float* __restrict__ w,
    const float* __restrict__ a,
    unsigned short* __restrict__ whB, float* __restrict__ wh1p,
    float* __restrict__ wh2p)
{
    __shared__ float hs[16 * 128];
    __shared__ float whs[16][64];
    const int t = threadIdx.x;

    if (blockIdx.x < 2048) {
        // ---- compress: 2048 blocks x 256 thr x 16 iters x 8 ints = 64M ints ----
        const size_t base = (size_t)blockIdx.x * 256 + t;
        #pragma unroll
        for (int it = 0; it < 16; ++it) {
            const size_t G = (size_t)it * 524288 + base;   // byte index
            const int4* p = (const int4*)(adj + G * 8);
            int4 v0 = p[0], v1 = p[1];
            unsigned b = 0;
            b |= (unsigned)(v0.x > 0) << 0;
            b |= (unsigned)(v0.y > 0) << 1;
            b |= (unsigned)(v0.z > 0) << 2;
            b |= (unsigned)(v0.w > 0) << 3;
            b |= (unsigned)(v1.x > 0) << 4;
            b |= (unsigned)(v1.y > 0) << 5;
            b |= (unsigned)(v1.z > 0) << 6;
            b |= (unsigned)(v1.w > 0) << 7;
            bm[G] = (unsigned char)b;
        }
        return;
    }

    // ---- prep: 512 blocks of 16 rows ----
    const int i0 = (blockIdx.x - 2048) * 16;

    const float* hsrc = h + (size_t)i0 * D_IN;
    *(float4*)(hs + t * 8)     = *(const float4*)(hsrc + t * 8);
    *(float4*)(hs + t * 8 + 4) = *(const float4*)(hsrc + t * 8 + 4);
    __syncthreads();

    const int r  = t >> 4;          // local row 0..15
    const int og = (t & 15) * 4;    // 4 output dims
    f32x4 acc = {0.f, 0.f, 0.f, 0.f};
    for (int k = 0; k < D_IN; ++k) {
        float hv = hs[r * 128 + k];
        float4 wv = *(const float4*)(w + k * D_OUT + og);
        acc[0] += hv * wv.x; acc[1] += hv * wv.y;
        acc[2] += hv * wv.z; acc[3] += hv * wv.w;
    }
    whs[r][og]     = acc[0];
    whs[r][og + 1] = acc[1];
    whs[r][og + 2] = acc[2];
    whs[r][og + 3] = acc[3];

    float p1 = acc[0]*a[og] + acc[1]*a[og+1] + acc[2]*a[og+2] + acc[3]*a[og+3];
    float p2 = acc[0]*a[64+og] + acc[1]*a[64+og+1] + acc[2]*a[64+og+2] + acc[3]*a[64+og+3];
    #pragma unroll
    for (int m = 1; m < 16; m <<= 1) {
        p1 += __shfl_xor(p1, m);
        p2 += __shfl_xor(p2, m);
    }
    if ((t & 15) == 0) {
        wh1p[i0 + r] = p1 * LOG2E;
        wh2p[i0 + r] = p2 * LOG2E;
    }
    __syncthreads();

    {
        const int half = t >> 7;         // which 8-row group
        const int dim  = (t >> 1) & 63;
        const int e0   = (t & 1) * 4;
        ushort4 v;
        v.x = f32_bf16(whs[half * 8 + e0 + 0][dim]);
        v.y = f32_bf16(whs[half * 8 + e0 + 1][dim]);
        v.z = f32_bf16(whs[half * 8 + e0 + 2][dim]);
        v.w = f32_bf16(whs[half * 8 + e0 + 3][dim]);
        *(ushort4*)(whB + (size_t)(i0 / 8 + half) * 512 + dim * 8 + e0) = v;
    }
}

static __device__ __forceinline__ short8 pack8_bf16(const float* p) {
    union { unsigned int u[4]; short8 s; } r;
    asm("v_cvt_pk_bf16_f32 %0, %1, %2" : "=v"(r.u[0]) : "v"(p[0]), "v"(p[1]));
    asm("v_cvt_pk_bf16_f32 %0, %1, %2" : "=v"(r.u[1]) : "v"(p[2]), "v"(p[3]));
    asm("v_cvt_pk_bf16_f32 %0, %1, %2" : "=v"(r.u[2]) : "v"(p[4]), "v"(p[5]));
    asm("v_cvt_pk_bf16_f32 %0, %1, %2" : "=v"(r.u[3]) : "v"(p[6]), "v"(p[7]));
    return r.s;
}

// ---- Kernel 2: bitmask-driven fused softmax + att@wh + bias + elu ----
// 256 blocks x 512 thr (8 waves). Block owns 32 rows; wave wv owns cols
// [wv*1024,(wv+1)*1024) = 32 tiles of 32. Bitmask slice (32KB) + wh2p (32KB)
// staged to LDS once; no barriers in the main loop.
__global__ __launch_bounds__(512) void gat_main(
    const unsigned int* __restrict__ bm, const unsigned short* __restrict__ whB,
    const float* __restrict__ wh1p, const float* __restrict__ wh2p,
    const float* __restrict__ bias, float* __restrict__ out)
{
    __shared__ alignas(16) char smem[66560];
    unsigned int (*bmlds)[260] = (unsigned int(*)[260])smem;          // [32][260]
    float* w2lds = (float*)(smem + 33280);                            // [8192]
    float (*nums)[32][64] = (float(*)[32][64])smem;                   // [8][32][64]
    float (*dens)[32] = (float(*)[32])(smem + 65536);                 // [8][32]

    const int t    = threadIdx.x;
    const int wv   = t >> 6;
    const int lane = t & 63;
    const int il   = lane & 15;
    const int kg   = lane >> 4;
    const int r0   = blockIdx.x * 32;

    // stage bitmask rows [r0, r0+32) (8192 dwords) and wh2p (8192 floats)
    {
        const uint4*  bmg = (const uint4*)(bm + r0 * 256);
        const float4* w2g = (const float4*)wh2p;
        #pragma unroll
        for (int q = 0; q < 4; ++q) {
            const int C = q * 512 + t;
            uint4 v = bmg[C];
            const int rr = C >> 6, cc = (C & 63) * 4;
            *(uint4*)&bmlds[rr][cc] = v;
            float4 wv2 = w2g[C];
            *(float4*)&w2lds[C * 4] = wv2;
        }
    }
    __syncthreads();

    const float c0 = wh1p[r0 + il];
    const float c1 = wh1p[r0 + 16 + il];
    const int shk = kg * 8;

    f32x4 acc[2][4] = {};
    float den0 = 0.f, den1 = 0.f;

    #pragma unroll 4
    for (int n = 0; n < 32; ++n) {
        const int jd = wv * 32 + n;      // dword (32-col) index
        const int j0 = jd * 32;          // global col

        unsigned int m0 = bmlds[il][jd] >> shk;
        unsigned int m1 = bmlds[16 + il][jd] >> shk;
        float4 W0 = *(const float4*)&w2lds[j0 + kg * 8];
        float4 W1 = *(const float4*)&w2lds[j0 + kg * 8 + 4];

        const unsigned short* bb = whB + (size_t)(j0 / 8 + kg) * 512 + il * 8;
        short8 b0 = *(const short8*)(bb);
        short8 b1 = *(const short8*)(bb + 128);
        short8 b2 = *(const short8*)(bb + 256);
        short8 b3 = *(const short8*)(bb + 384);

        float wvv[8] = {W0.x, W0.y, W0.z, W0.w, W1.x, W1.y, W1.z, W1.w};
        float p0[8], p1[8];
        #pragma unroll
        for (int e = 0; e < 8; ++e) {
            float x = c0 + wvv[e];
            x = fmaxf(x, GAT_ALPHA * x);
            float p = __builtin_amdgcn_exp2f(x);
            p = (m0 & (1u << e)) ? p : 0.f;
            den0 += p; p0[e] = p;
            float y = c1 + wvv[e];
            y = fmaxf(y, GAT_ALPHA * y);
            float q = __builtin_amdgcn_exp2f(y);
            q = (m1 & (1u << e)) ? q : 0.f;
            den1 += q; p1[e] = q;
        }
        short8 af0 = pack8_bf16(p0);
        short8 af1 = pack8_bf16(p1);

        acc[0][0] = __builtin_amdgcn_mfma_f32_16x16x32_bf16(af0, b0, acc[0][0], 0, 0, 0);
        acc[1][0] = __builtin_amdgcn_mfma_f32_16x16x32_bf16(af1, b0, acc[1][0], 0, 0, 0);
        acc[0][1] = __builtin_amdgcn_mfma_f32_16x16x32_bf16(af0, b1, acc[0][1], 0, 0, 0);
        acc[1][1] = __builtin_amdgcn_mfma_f32_16x16x32_bf16(af1, b1, acc[1][1], 0, 0, 0);
        acc[0][2] = __builtin_amdgcn_mfma_f32_16x16x32_bf16(af0, b2, acc[0][2], 0, 0, 0);
        acc[1][2] = __builtin_amdgcn_mfma_f32_16x16x32_bf16(af1, b2, acc[1][2], 0, 0, 0);
        acc[0][3] = __builtin_amdgcn_mfma_f32_16x16x32_bf16(af0, b3, acc[0][3], 0, 0, 0);
        acc[1][3] = __builtin_amdgcn_mfma_f32_16x16x32_bf16(af1, b3, acc[1][3], 0, 0, 0);
    }

    // reduce den over kg (lanes il, il+16, il+32, il+48)
    den0 += __shfl_xor(den0, 16); den0 += __shfl_xor(den0, 32);
    den1 += __shfl_xor(den1, 16); den1 += __shfl_xor(den1, 32);

    __syncthreads();   // all bmlds/w2lds reads done; safe to overwrite smem

    if (kg == 0) { dens[wv][il] = den0; dens[wv][16 + il] = den1; }
    #pragma unroll
    for (int q = 0; q < 4; ++q) {
        #pragma unroll
        for (int d = 0; d < 4; ++d) {
            nums[wv][kg * 4 + q][d * 16 + il]      = acc[0][d][q];
            nums[wv][16 + kg * 4 + q][d * 16 + il] = acc[1][d][q];
        }
    }
    __syncthreads();

    #pragma unroll
    for (int k = 0; k < 4; ++k) {
        const int idx = k * 512 + t;
        const int rr = idx >> 6, cc = idx & 63;
        float s = 0.f, dd = 0.f;
        #pragma unroll
        for (int w8 = 0; w8 < 8; ++w8) { s += nums[w8][rr][cc]; dd += dens[w8][rr]; }
        float val = s / dd + bias[cc];
        out[(size_t)(r0 + rr) * D_OUT + cc] =
            val > 0.f ? val : (__builtin_amdgcn_exp2f(val * LOG2E) - 1.f);
    }
}

extern "C" void kernel_launch(void* const* d_in, const int* in_sizes, int n_in,
                              void* d_out, int out_size, void* d_ws, size_t ws_size,
                              hipStream_t stream) {
    const float* h   = (const float*)d_in[0];
    const int*   adj = (const int*)d_in[1];
    const float* w   = (const float*)d_in[2];
    const float* a   = (const float*)d_in[3];
    const float* b   = (const float*)d_in[4];
    float* out = (float*)d_out;

    char* ws = (char*)d_ws;
    unsigned short* whB = (unsigned short*)ws;                        // 1 MB
    float* wh1p = (float*)(ws + (size_t)D_OUT * NN * 2);              // 32 KB
    float* wh2p = (float*)(ws + (size_t)D_OUT * NN * 2 + NN * 4);     // 32 KB
    unsigned char* bm = (unsigned char*)(ws + (size_t)D_OUT * NN * 2 + NN * 8);  // 8 MB

    gat_pre<<<2560, 256, 0, stream>>>(adj, bm, h, w, a, whB, wh1p, wh2p);
    gat_main<<<256, 512, 0, stream>>>((const unsigned int*)bm, whB, wh1p, wh2p, b, out);
}